// Round 17
// baseline (5273.427 us; speedup 1.0000x reference)
//
#include <hip/hip_runtime.h>
#include <hip/hip_bf16.h>

#define D_MODEL 128
#define INNER 256
#define NH 4
#define DHM 64
#define SNH 4
#define SDH 32
#define FF 192
#define CK 4
#define BATCH 64
#define SEQ 256
#define T_TOK (BATCH*SEQ)   /* 16384 tokens */

typedef __hip_bfloat16 bf16;

__device__ __forceinline__ float sigf(float x){ return 1.0f/(1.0f+__expf(-x)); }

// ---------------- sentinel writer (fp32) ----------------
__global__ void sentinel_kernel(float* __restrict__ out, float v)
{
    int idx = threadIdx.x;
    if (idx < BATCH*3) out[idx] = v;
}

// ---------------- embed ----------------
__global__ void embed_kernel(const float* __restrict__ x, const float* __restrict__ W,
                             const float* __restrict__ bias, float* __restrict__ h)
{
    int idx = blockIdx.x*blockDim.x + threadIdx.x;   // T*128
    if (idx >= T_TOK*D_MODEL) return;
    int d = idx & 127; int t = idx >> 7;
    float s = bias[d];
    #pragma unroll
    for (int i = 0; i < 3; ++i) s += x[t*3+i] * W[i*D_MODEL+d];
    h[idx] = s;
}

// ---------------- LN: one WAVE (64 threads) per token, coalesced ----------------
__global__ void ln_kernel(const float* __restrict__ x, const float* __restrict__ w,
                          float* __restrict__ out)
{
    int t = blockIdx.x; int lane = threadIdx.x;      // 64 threads
    float v0 = x[(size_t)t*128 + lane], v1 = x[(size_t)t*128 + 64 + lane];
    float s = v0 + v1, ss = v0*v0 + v1*v1;
    #pragma unroll
    for (int off = 32; off >= 1; off >>= 1){ s += __shfl_xor(s,off); ss += __shfl_xor(ss,off); }
    float mu  = s * (1.f/128.f);
    float var = fmaxf(ss * (1.f/128.f) - mu*mu, 0.f);
    float r   = rsqrtf(var + 1e-6f);
    out[(size_t)t*128 + lane]      = (v0-mu)*r*w[lane];
    out[(size_t)t*128 + 64 + lane] = (v1-mu)*r*w[64+lane];
}

// ---------------- GEMM: C[M,N] (+)= A[M,K] * W[K,N], 4-way ILP ----------------
__global__ void gemm_kernel(const float* __restrict__ A, const float* __restrict__ W,
                            float* __restrict__ C, int M, int N, int Kd, int acc)
{
    int idx = blockIdx.x*blockDim.x + threadIdx.x;
    if (idx >= M*N) return;
    int m = idx / N, n = idx - m*N;
    const float* a = A + (size_t)m*Kd;
    const float* w = W + n;
    float s0 = 0.f, s1 = 0.f, s2 = 0.f, s3 = 0.f;
    #pragma unroll 4
    for (int k = 0; k < Kd; k += 4){
        s0 = fmaf(a[k  ], w[(size_t)(k  )*N], s0);
        s1 = fmaf(a[k+1], w[(size_t)(k+1)*N], s1);
        s2 = fmaf(a[k+2], w[(size_t)(k+2)*N], s2);
        s3 = fmaf(a[k+3], w[(size_t)(k+3)*N], s3);
    }
    float s = (s0+s1) + (s2+s3);
    if (acc) C[idx] += s; else C[idx] = s;
}

// ---------------- causal conv (K=4) + silu ----------------
__global__ void conv_silu_kernel(const float* __restrict__ in, int istride,
                                 const float* __restrict__ w, const float* __restrict__ bias,
                                 float* __restrict__ out, int C)
{
    int idx = blockIdx.x*blockDim.x + threadIdx.x;   // T*C
    if (idx >= T_TOK*C) return;
    int c = idx % C; int t = idx / C;
    int s = t & (SEQ-1); int b = t >> 8;
    float a = bias[c];
    int j0 = (s >= CK-1) ? s-(CK-1) : 0;
    for (int j = j0; j <= s; ++j){
        int k = j - s + (CK-1);
        a += in[(size_t)(b*SEQ+j)*istride + c] * w[c*CK + k];
    }
    out[idx] = a * sigf(a);
}

// ---------------- headwise 4x4 projection ----------------
__global__ void headwise_kernel(const float* __restrict__ in, int istride,
                                const float* __restrict__ W, float* __restrict__ out)
{
    int idx = blockIdx.x*blockDim.x + threadIdx.x;   // T*256
    if (idx >= T_TOK*INNER) return;
    int c = idx & 255; int t = idx >> 8;
    int n = c >> 2, l = c & 3;
    const float* xr = in + (size_t)t*istride + n*4;
    float s = 0.f;
    for (int k = 0; k < 4; ++k) s += xr[k] * W[n*16 + k*4 + l];
    out[idx] = s;
}

__global__ void headwise_inplace_kernel(float* __restrict__ up, const float* __restrict__ W)
{
    int idx = blockIdx.x*blockDim.x + threadIdx.x;   // T*64
    if (idx >= T_TOK*64) return;
    int n = idx & 63; int t = idx >> 6;
    float* xr = up + (size_t)t*512 + n*4;
    float x0 = xr[0], x1 = xr[1], x2 = xr[2], x3 = xr[3];
    const float* w = W + n*16;
    for (int l = 0; l < 4; ++l)
        xr[l] = x0*w[l] + x1*w[4+l] + x2*w[8+l] + x3*w[12+l];
}

// ---------------- ig/fg projection ----------------
__global__ void gateproj_kernel(const float* __restrict__ q, const float* __restrict__ k,
                                const float* __restrict__ up,
                                const float* __restrict__ Wig, const float* __restrict__ big,
                                const float* __restrict__ Wfg, const float* __restrict__ bfg,
                                float* __restrict__ igt, float* __restrict__ fgt)
{
    int idx = blockIdx.x*blockDim.x + threadIdx.x;   // T*4
    if (idx >= T_TOK*NH) return;
    int hh = idx & 3; int t = idx >> 2;
    int b = t >> 8, s = t & 255;
    float si = big[hh], sf = bfg[hh];
    for (int j = 0; j < 3*INNER; ++j){
        float xv = (j < 256) ? q[(size_t)t*256 + j]
                 : (j < 512) ? k[(size_t)t*256 + j - 256]
                             : up[(size_t)t*512 + j - 512];   // v in up[:, :256]
        si += xv * Wig[j*4 + hh];
        sf += xv * Wfg[j*4 + hh];
    }
    igt[(b*4+hh)*SEQ + s] = si;
    fgt[(b*4+hh)*SEQ + s] = sf;
}

__global__ void cs_kernel(const float* __restrict__ fgt, float* __restrict__ cs)
{
    int bh = blockIdx.x*blockDim.x + threadIdx.x;    // 256
    if (bh >= BATCH*NH) return;
    float run = 0.f;
    for (int s = 0; s < SEQ; ++s){
        float f = fgt[bh*SEQ+s];
        float lf = (f > 0.f) ? -log1pf(__expf(-f)) : f - log1pf(__expf(f));
        run += lf;
        cs[bh*SEQ+s] = run;
    }
}

__global__ void maxd_kernel(const float* __restrict__ cs, const float* __restrict__ igt,
                            float* __restrict__ maxd)
{
    int idx = blockIdx.x*blockDim.x + threadIdx.x;   // 65536
    if (idx >= BATCH*NH*SEQ) return;
    int i = idx & 255; int bh = idx >> 8;
    float csi = cs[bh*SEQ+i];
    float m = -1e30f;
    for (int j = 0; j <= i; ++j) m = fmaxf(m, csi - cs[bh*SEQ+j] + igt[bh*SEQ+j]);
    maxd[idx] = m;
}

// ---------------- attention: block per (b,h), thread per row, k/v in LDS ----------
#define ACHUNK 64
__global__ void __launch_bounds__(256, 2)
attn_kernel(float* __restrict__ q, const float* __restrict__ kk,
            const float* __restrict__ up,
            const float* __restrict__ igt, const float* __restrict__ cs,
            const float* __restrict__ maxd)
{
    int bh = blockIdx.x; int b = bh >> 2, hh = bh & 3;
    int i = threadIdx.x;                             // 256 threads = rows
    __shared__ float k_sh[ACHUNK][DHM];
    __shared__ float v_sh[ACHUNK][DHM];
    __shared__ float cs_sh[SEQ], ig_sh[SEQ];
    cs_sh[i] = cs[bh*SEQ+i];
    ig_sh[i] = igt[bh*SEQ+i];
    int t_i = b*SEQ + i;
    float csi_g = cs[bh*SEQ+i];
    float m     = maxd[bh*SEQ+i];
    float* qp = q + (size_t)t_i*INNER + hh*DHM;
    float qr[DHM];
    #pragma unroll
    for (int d = 0; d < DHM; ++d) qr[d] = qp[d];
    float acc[DHM];
    #pragma unroll
    for (int d = 0; d < DHM; ++d) acc[d] = 0.f;
    float ssum = 0.f;
    for (int c0 = 0; c0 < SEQ; c0 += ACHUNK){
        __syncthreads();
        for (int idx2 = threadIdx.x; idx2 < ACHUNK*DHM; idx2 += blockDim.x){
            int j = idx2 >> 6, d = idx2 & 63;
            size_t t_j = (size_t)(b*SEQ + c0 + j);
            k_sh[j][d] = kk[t_j*INNER + hh*DHM + d];
            v_sh[j][d] = up[t_j*512  + hh*DHM + d];
        }
        __syncthreads();
        int jend = (i < c0 + ACHUNK - 1) ? i : (c0 + ACHUNK - 1);
        for (int j = c0; j <= jend; ++j){
            int jj = j - c0;
            const float4* k4 = (const float4*)k_sh[jj];
            float d0 = 0.f, d1 = 0.f, d2 = 0.f, d3 = 0.f;
            #pragma unroll
            for (int d4 = 0; d4 < 16; d4 += 4){
                float4 ka = k4[d4],   kb2 = k4[d4+1];
                float4 kc = k4[d4+2], kd  = k4[d4+3];
                d0 += qr[4*d4   ]*ka.x  + qr[4*d4+1 ]*ka.y  + qr[4*d4+2 ]*ka.z  + qr[4*d4+3 ]*ka.w;
                d1 += qr[4*d4+4 ]*kb2.x + qr[4*d4+5 ]*kb2.y + qr[4*d4+6 ]*kb2.z + qr[4*d4+7 ]*kb2.w;
                d2 += qr[4*d4+8 ]*kc.x  + qr[4*d4+9 ]*kc.y  + qr[4*d4+10]*kc.z  + qr[4*d4+11]*kc.w;
                d3 += qr[4*d4+12]*kd.x  + qr[4*d4+13]*kd.y  + qr[4*d4+14]*kd.z  + qr[4*d4+15]*kd.w;
            }
            float dot = (d0+d1) + (d2+d3);
            float arg = fminf(csi_g - cs_sh[j] + ig_sh[j] - m, 0.f);
            float cij = dot * 0.125f * __expf(arg);
            ssum += cij;
            const float4* v4 = (const float4*)v_sh[jj];
            #pragma unroll
            for (int d4 = 0; d4 < 16; ++d4){
                float4 vv = v4[d4];
                acc[4*d4]   += cij*vv.x; acc[4*d4+1] += cij*vv.y;
                acc[4*d4+2] += cij*vv.z; acc[4*d4+3] += cij*vv.w;
            }
        }
    }
    float nrm = fmaxf(fabsf(ssum), __expf(-m)) + 1e-6f;
    float rn = 1.f/nrm;
    #pragma unroll
    for (int d = 0; d < DHM; ++d) qp[d] = acc[d]*rn;
}

__global__ void mh_gate_kernel(float* __restrict__ q, const float* __restrict__ up,
                               const float* __restrict__ xc,
                               const float* __restrict__ gnw, const float* __restrict__ skip)
{
    int idx = blockIdx.x*blockDim.x + threadIdx.x;   // T*4
    if (idx >= T_TOK*NH) return;
    int hh = idx & 3; int t = idx >> 2;
    float* qp = q + (size_t)t*256 + hh*DHM;
    float s = 0.f;
    for (int d = 0; d < DHM; ++d) s += qp[d];
    float mu = s * (1.f/64.f);
    float v = 0.f;
    for (int d = 0; d < DHM; ++d){ float dv = qp[d]-mu; v += dv*dv; }
    float r = rsqrtf(v * (1.f/64.f) + 1e-6f);
    for (int d = 0; d < DHM; ++d){
        int c = hh*DHM + d;
        float hn = (qp[d]-mu)*r*gnw[c];
        float z  = up[(size_t)t*512 + 256 + c];
        qp[d] = (hn + skip[c]*xc[(size_t)t*256 + c]) * (z*sigf(z));
    }
}

// ---------------- sLSTM gate pre-activations, scan-friendly layout ----------------
// out[((b*4+n)*SEQ + s)*128 + l*4 + g]  (lane l's 4 gates contiguous as float4)
__global__ void slstm_gates_kernel(const float* __restrict__ xc, const float* __restrict__ xl,
                                   const float* __restrict__ Wg, const float* __restrict__ bg,
                                   float* __restrict__ gates)
{
    int idx = blockIdx.x*blockDim.x + threadIdx.x;   // T*512, g fastest
    if (idx >= T_TOK*512) return;
    int g = idx & 3; int rest = idx >> 2;
    int l = rest & 31; rest >>= 5;
    int n = rest & 3;  int t = rest >> 2;
    int b = t >> 8, s = t & 255;
    const float* in = (g < 2) ? xc : xl;
    const float* xr = in + (size_t)t*128 + n*32;
    const float* w  = Wg + (g*4+n)*1024 + l;
    float s0 = 0.f, s1 = 0.f, s2 = 0.f, s3 = 0.f;
    #pragma unroll
    for (int k = 0; k < 32; k += 4){
        s0 = fmaf(xr[k  ], w[(k  )*32], s0);
        s1 = fmaf(xr[k+1], w[(k+1)*32], s1);
        s2 = fmaf(xr[k+2], w[(k+2)*32], s2);
        s3 = fmaf(xr[k+3], w[(k+3)*32], s3);
    }
    gates[(size_t)((b*4+n)*SEQ + s)*128 + l*4 + g] =
        bg[g*128 + n*32 + l] + (s0+s1) + (s2+s3);
}

// ---------------- sLSTM recurrence: block per (b,n), float4 gates + prefetch -------
__global__ void slstm_scan_kernel(const float* __restrict__ gates, const float* __restrict__ Rw,
                                  float* __restrict__ ys)
{
    int bn = blockIdx.x;                 // b*4 + n
    int b = bn >> 2, n = bn & 3;
    int l = threadIdx.x;                 // 32
    __shared__ float R_sh[4][32][32];    // [g][k][l]
    __shared__ float h_sh[32];
    for (int i2 = l; i2 < 4096; i2 += 32){
        int g = i2 >> 10, k = (i2 >> 5) & 31, ll = i2 & 31;
        R_sh[g][k][ll] = Rw[(g*4+n)*1024 + k*32 + ll];
    }
    h_sh[l] = 0.f;
    float c = 0.f, nst = 0.f, m = 0.f;
    __syncthreads();
    const float* gbase = gates + (size_t)bn*SEQ*128;
    float4 gcur = ((const float4*)gbase)[l];         // s = 0
    for (int s = 0; s < SEQ; ++s){
        float4 gnext;
        if (s+1 < SEQ) gnext = ((const float4*)(gbase + (size_t)(s+1)*128))[l];
        else           gnext = make_float4(0.f,0.f,0.f,0.f);
        float r0=0.f, r1=0.f, r2=0.f, r3=0.f;
        #pragma unroll 8
        for (int k = 0; k < 32; ++k){
            float hv = h_sh[k];
            r0 += hv * R_sh[0][k][l];
            r1 += hv * R_sh[1][k][l];
            r2 += hv * R_sh[2][k][l];
            r3 += hv * R_sh[3][k][l];
        }
        float ir  = gcur.x + r0;
        float fr  = gcur.y + r1;
        float zr  = gcur.z + r2;
        float orr = gcur.w + r3;
        float mnew = fmaxf(fr + m, ir);
        float iv = __expf(ir - mnew);
        float fv = __expf(fr + m - mnew);
        float zt = tanhf(zr);
        float ov = sigf(orr);
        c   = fv*c + iv*zt;
        nst = fv*nst + iv;
        float hst = ov * c / (nst + 1e-8f);
        m = mnew;
        __syncthreads();
        h_sh[l] = hst;
        ys[(size_t)(b*SEQ + s)*128 + n*32 + l] = hst;
        gcur = gnext;
        __syncthreads();
    }
}

__global__ void mh_add_kernel(const float* __restrict__ ys, const float* __restrict__ gnw,
                              float* __restrict__ h)
{
    int idx = blockIdx.x*blockDim.x + threadIdx.x;   // T*4
    if (idx >= T_TOK*SNH) return;
    int n = idx & 3; int t = idx >> 2;
    const float* yr = ys + (size_t)t*128 + n*32;
    float s = 0.f;
    for (int l = 0; l < 32; ++l) s += yr[l];
    float mu = s * (1.f/32.f);
    float v = 0.f;
    for (int l = 0; l < 32; ++l){ float dv = yr[l]-mu; v += dv*dv; }
    float r = rsqrtf(v * (1.f/32.f) + 1e-6f);
    for (int l = 0; l < 32; ++l)
        h[(size_t)t*128 + n*32 + l] += (yr[l]-mu)*r*gnw[n*32+l];
}

__global__ void geluv_kernel(const float* __restrict__ up, float* __restrict__ out)
{
    int idx = blockIdx.x*blockDim.x + threadIdx.x;   // T*192
    if (idx >= T_TOK*FF) return;
    int j = idx % FF; int t = idx / FF;
    float g  = up[(size_t)t*384 + j];
    float vv = up[(size_t)t*384 + FF + j];
    float gel = 0.5f*g*(1.f + tanhf(0.7978845608028654f*(g + 0.044715f*g*g*g)));
    out[idx] = gel*vv;
}

// ---------------- final projection: fp32 output ----------------
__global__ void out_kernel(const float* __restrict__ ln, const float* __restrict__ W,
                           const float* __restrict__ bias, float* __restrict__ out)
{
    int idx = threadIdx.x;                           // 192 threads, 1 block
    if (idx >= BATCH*3) return;
    int b = idx / 3, e = idx % 3;
    float s = bias[e];
    const float* xr = ln + ((size_t)(b*SEQ + SEQ-1))*128;
    for (int d = 0; d < 128; ++d) s += xr[d]*W[d*3+e];
    out[idx] = s;
}

#define LCHK do { \
    if (hipGetLastError() != hipSuccess){ \
        sentinel_kernel<<<1, 192, 0, stream>>>((float*)d_out, 3000.0f + 32.0f*(float)launch_idx); \
        return; } \
    ++launch_idx; } while(0)

extern "C" void kernel_launch(void* const* d_in, const int* in_sizes, int n_in,
                              void* d_out, int out_size, void* d_ws, size_t ws_size,
                              hipStream_t stream)
{
    (void)out_size;
    static const int expected_sizes[30] = {
        49152, 384, 128, 512, 262144, 4096, 1024, 4096, 4096, 4096,
        12288, 16, 12288, 16, 1024, 1024, 131072, 256, 1024, 256,
        32768, 1024, 32768, 256, 256, 98304, 49152, 128, 384, 3
    };
    if (n_in != 30){ sentinel_kernel<<<1,192,0,stream>>>((float*)d_out, 5000.0f); return; }
    for (int i = 0; i < 30; ++i)
        if (in_sizes[i] != expected_sizes[i]){
            sentinel_kernel<<<1,192,0,stream>>>((float*)d_out, 2000.0f + 32.0f*i); return; }
    if (ws_size < (size_t)96*1024*1024){
        sentinel_kernel<<<1,192,0,stream>>>((float*)d_out, 1000.0f + (float)(ws_size >> 20)); return; }

    const float* x        = (const float*)d_in[0];
    const float* W_emb    = (const float*)d_in[1];
    const float* b_emb    = (const float*)d_in[2];
    const float* m_ln_w   = (const float*)d_in[3];
    const float* m_Wup    = (const float*)d_in[4];
    const float* m_conv_w = (const float*)d_in[5];
    const float* m_conv_b = (const float*)d_in[6];
    const float* m_Wq     = (const float*)d_in[7];
    const float* m_Wk     = (const float*)d_in[8];
    const float* m_Wv     = (const float*)d_in[9];
    const float* m_Wig    = (const float*)d_in[10];
    const float* m_big    = (const float*)d_in[11];
    const float* m_Wfg    = (const float*)d_in[12];
    const float* m_bfg    = (const float*)d_in[13];
    const float* m_gn_w   = (const float*)d_in[14];
    const float* m_skip   = (const float*)d_in[15];
    const float* m_Wdown  = (const float*)d_in[16];
    const float* s_ln_w   = (const float*)d_in[17];
    const float* s_conv_w = (const float*)d_in[18];
    const float* s_conv_b = (const float*)d_in[19];
    const float* s_Wg     = (const float*)d_in[20];
    const float* s_bg     = (const float*)d_in[21];
    const float* s_R      = (const float*)d_in[22];
    const float* s_gn_w   = (const float*)d_in[23];
    const float* s_ln2_w  = (const float*)d_in[24];
    const float* s_Wff_up = (const float*)d_in[25];
    const float* s_Wff_dn = (const float*)d_in[26];
    const float* post_ln  = (const float*)d_in[27];
    const float* W_out    = (const float*)d_in[28];
    const float* b_out    = (const float*)d_in[29];

    float* ws  = (float*)d_ws;
    float* h   = ws;                         // T*128
    float* ln  = h   + (size_t)T_TOK*128;    // T*128; igt/fgt/cs/maxd alias (ln dead then)
    float* up  = ln  + (size_t)T_TOK*128;    // T*512
    float* xc  = up  + (size_t)T_TOK*512;    // T*256
    float* qb  = xc  + (size_t)T_TOK*256;    // T*256
    float* kb  = qb  + (size_t)T_TOK*256;    // T*256 (k; sLSTM ys)
    float* igt  = ln;
    float* fgt  = ln + 65536;
    float* csb  = ln + 2*65536;
    float* maxd = ln + 3*65536;

    int launch_idx = 0;
    (void)hipGetLastError();

    embed_kernel<<<(T_TOK*128)/256, 256, 0, stream>>>(x, W_emb, b_emb, h); LCHK;

    const char* bt = "msmsmm";
    int mi = 0, si = 0;
    for (int blk = 0; blk < 6; ++blk){
        if (bt[blk] == 'm'){
            ln_kernel<<<T_TOK, 64, 0, stream>>>(h, m_ln_w + mi*128, ln); LCHK;
            gemm_kernel<<<(T_TOK*512)/256, 256, 0, stream>>>(ln, m_Wup + (size_t)mi*65536, up, T_TOK, 512, 128, 0); LCHK;
            conv_silu_kernel<<<(T_TOK*256)/256, 256, 0, stream>>>(up, 512, m_conv_w + mi*1024, m_conv_b + mi*256, xc, 256); LCHK;
            headwise_kernel<<<(T_TOK*256)/256, 256, 0, stream>>>(xc, 256, m_Wq + mi*1024, qb); LCHK;
            headwise_kernel<<<(T_TOK*256)/256, 256, 0, stream>>>(xc, 256, m_Wk + mi*1024, kb); LCHK;
            headwise_inplace_kernel<<<(T_TOK*64)/256, 256, 0, stream>>>(up, m_Wv + mi*1024); LCHK;
            gateproj_kernel<<<(T_TOK*4)/256, 256, 0, stream>>>(qb, kb, up, m_Wig + mi*3072, m_big + mi*4,
                                                               m_Wfg + mi*3072, m_bfg + mi*4, igt, fgt); LCHK;
            cs_kernel<<<4, 64, 0, stream>>>(fgt, csb); LCHK;
            maxd_kernel<<<256, 256, 0, stream>>>(csb, igt, maxd); LCHK;
            attn_kernel<<<256, 256, 0, stream>>>(qb, kb, up, igt, csb, maxd); LCHK;
            mh_gate_kernel<<<(T_TOK*4)/256, 256, 0, stream>>>(qb, up, xc, m_gn_w + mi*256, m_skip + mi*256); LCHK;
            gemm_kernel<<<(T_TOK*128)/256, 256, 0, stream>>>(qb, m_Wdown + (size_t)mi*32768, h, T_TOK, 128, 256, 1); LCHK;
            ++mi;
        } else {
            ln_kernel<<<T_TOK, 64, 0, stream>>>(h, s_ln_w + si*128, ln); LCHK;
            conv_silu_kernel<<<(T_TOK*128)/256, 256, 0, stream>>>(ln, 128, s_conv_w + si*512, s_conv_b + si*128, xc, 128); LCHK;
            slstm_gates_kernel<<<(T_TOK*512)/256, 256, 0, stream>>>(xc, ln, s_Wg + si*16384, s_bg + si*512, up); LCHK;
            slstm_scan_kernel<<<BATCH*4, 32, 0, stream>>>(up, s_R + si*16384, kb); LCHK;
            mh_add_kernel<<<(T_TOK*4)/256, 256, 0, stream>>>(kb, s_gn_w + si*128, h); LCHK;
            ln_kernel<<<T_TOK, 64, 0, stream>>>(h, s_ln2_w + si*128, ln); LCHK;
            gemm_kernel<<<(T_TOK*384)/256, 256, 0, stream>>>(ln, s_Wff_up + (size_t)si*49152, up, T_TOK, 384, 128, 0); LCHK;
            geluv_kernel<<<(T_TOK*192)/256, 256, 0, stream>>>(up, qb); LCHK;
            gemm_kernel<<<(T_TOK*128)/256, 256, 0, stream>>>(qb, s_Wff_dn + (size_t)si*24576, h, T_TOK, 128, 192, 1); LCHK;
            ++si;
        }
    }

    ln_kernel<<<T_TOK, 64, 0, stream>>>(h, post_ln, ln); LCHK;
    out_kernel<<<1, 192, 0, stream>>>(ln, W_out, b_out, (float*)d_out); LCHK;
}

// Round 18
// 3817.325 us; speedup vs baseline: 1.3814x; 1.3814x over previous
//
#include <hip/hip_runtime.h>
#include <hip/hip_bf16.h>

#define D_MODEL 128
#define INNER 256
#define NH 4
#define DHM 64
#define SNH 4
#define SDH 32
#define FF 192
#define CK 4
#define BATCH 64
#define SEQ 256
#define T_TOK (BATCH*SEQ)   /* 16384 tokens */

typedef __hip_bfloat16 bf16;

__device__ __forceinline__ float sigf(float x){ return 1.0f/(1.0f+__expf(-x)); }

// ---------------- sentinel writer (fp32) ----------------
__global__ void sentinel_kernel(float* __restrict__ out, float v)
{
    int idx = threadIdx.x;
    if (idx < BATCH*3) out[idx] = v;
}

// ---------------- embed ----------------
__global__ void embed_kernel(const float* __restrict__ x, const float* __restrict__ W,
                             const float* __restrict__ bias, float* __restrict__ h)
{
    int idx = blockIdx.x*blockDim.x + threadIdx.x;   // T*128
    if (idx >= T_TOK*D_MODEL) return;
    int d = idx & 127; int t = idx >> 7;
    float s = bias[d];
    #pragma unroll
    for (int i = 0; i < 3; ++i) s += x[t*3+i] * W[i*D_MODEL+d];
    h[idx] = s;
}

// ---------------- LN: one WAVE (64 threads) per token, coalesced ----------------
__global__ void ln_kernel(const float* __restrict__ x, const float* __restrict__ w,
                          float* __restrict__ out)
{
    int t = blockIdx.x; int lane = threadIdx.x;      // 64 threads
    float v0 = x[(size_t)t*128 + lane], v1 = x[(size_t)t*128 + 64 + lane];
    float s = v0 + v1, ss = v0*v0 + v1*v1;
    #pragma unroll
    for (int off = 32; off >= 1; off >>= 1){ s += __shfl_xor(s,off); ss += __shfl_xor(ss,off); }
    float mu  = s * (1.f/128.f);
    float var = fmaxf(ss * (1.f/128.f) - mu*mu, 0.f);
    float r   = rsqrtf(var + 1e-6f);
    out[(size_t)t*128 + lane]      = (v0-mu)*r*w[lane];
    out[(size_t)t*128 + 64 + lane] = (v1-mu)*r*w[64+lane];
}

// ---------------- tiled GEMM: C[M,N] (+)= A[M,K] * W[K,N] ----------------
// 64x64 tile, 256 threads, 4x4 outputs/thread, TK=32. M%64==0, N%64==0, K%32==0.
#define TM 64
#define TN 64
#define TK 32
__global__ void __launch_bounds__(256)
gemm_tiled_kernel(const float* __restrict__ A, const float* __restrict__ W,
                  float* __restrict__ C, int M, int N, int Kd, int acc)
{
    int ntiles = N / TN;
    int bx = blockIdx.x % ntiles;
    int by = blockIdx.x / ntiles;
    __shared__ float As[TK][TM+1];   // +1 pad: kills 32-way write conflicts
    __shared__ float Ws[TK][TN];
    int tid = threadIdx.x;
    int tn = (tid & 15) * 4;         // col within tile
    int tm = (tid >> 4) * 4;         // row within tile
    float accr[4][4] = {{0.f}};
    for (int k0 = 0; k0 < Kd; k0 += TK){
        #pragma unroll
        for (int i = tid; i < TM*TK; i += 256){
            int c2 = i & 31, r = i >> 5;             // k fastest -> coalesced global
            As[c2][r] = A[(size_t)(by*TM + r)*Kd + k0 + c2];
        }
        #pragma unroll
        for (int i = tid; i < TK*TN; i += 256){
            int c2 = i & 63, r = i >> 6;             // n fastest -> coalesced global
            Ws[r][c2] = W[(size_t)(k0 + r)*N + bx*TN + c2];
        }
        __syncthreads();
        #pragma unroll
        for (int k = 0; k < TK; ++k){
            float a0 = As[k][tm], a1 = As[k][tm+1], a2 = As[k][tm+2], a3 = As[k][tm+3];
            float4 wv = *(const float4*)&Ws[k][tn];
            accr[0][0] = fmaf(a0, wv.x, accr[0][0]); accr[0][1] = fmaf(a0, wv.y, accr[0][1]);
            accr[0][2] = fmaf(a0, wv.z, accr[0][2]); accr[0][3] = fmaf(a0, wv.w, accr[0][3]);
            accr[1][0] = fmaf(a1, wv.x, accr[1][0]); accr[1][1] = fmaf(a1, wv.y, accr[1][1]);
            accr[1][2] = fmaf(a1, wv.z, accr[1][2]); accr[1][3] = fmaf(a1, wv.w, accr[1][3]);
            accr[2][0] = fmaf(a2, wv.x, accr[2][0]); accr[2][1] = fmaf(a2, wv.y, accr[2][1]);
            accr[2][2] = fmaf(a2, wv.z, accr[2][2]); accr[2][3] = fmaf(a2, wv.w, accr[2][3]);
            accr[3][0] = fmaf(a3, wv.x, accr[3][0]); accr[3][1] = fmaf(a3, wv.y, accr[3][1]);
            accr[3][2] = fmaf(a3, wv.z, accr[3][2]); accr[3][3] = fmaf(a3, wv.w, accr[3][3]);
        }
        __syncthreads();
    }
    #pragma unroll
    for (int i = 0; i < 4; ++i){
        size_t off = (size_t)(by*TM + tm + i)*N + bx*TN + tn;
        if (acc){
            float4 old = *(float4*)&C[off];
            old.x += accr[i][0]; old.y += accr[i][1];
            old.z += accr[i][2]; old.w += accr[i][3];
            *(float4*)&C[off] = old;
        } else {
            *(float4*)&C[off] = make_float4(accr[i][0], accr[i][1], accr[i][2], accr[i][3]);
        }
    }
}

// ---------------- causal conv (K=4) + silu ----------------
__global__ void conv_silu_kernel(const float* __restrict__ in, int istride,
                                 const float* __restrict__ w, const float* __restrict__ bias,
                                 float* __restrict__ out, int C)
{
    int idx = blockIdx.x*blockDim.x + threadIdx.x;   // T*C
    if (idx >= T_TOK*C) return;
    int c = idx % C; int t = idx / C;
    int s = t & (SEQ-1); int b = t >> 8;
    float a = bias[c];
    int j0 = (s >= CK-1) ? s-(CK-1) : 0;
    for (int j = j0; j <= s; ++j){
        int k = j - s + (CK-1);
        a += in[(size_t)(b*SEQ+j)*istride + c] * w[c*CK + k];
    }
    out[idx] = a * sigf(a);
}

// ---------------- headwise 4x4 projection ----------------
__global__ void headwise_kernel(const float* __restrict__ in, int istride,
                                const float* __restrict__ W, float* __restrict__ out)
{
    int idx = blockIdx.x*blockDim.x + threadIdx.x;   // T*256
    if (idx >= T_TOK*INNER) return;
    int c = idx & 255; int t = idx >> 8;
    int n = c >> 2, l = c & 3;
    const float* xr = in + (size_t)t*istride + n*4;
    float s = 0.f;
    for (int k = 0; k < 4; ++k) s += xr[k] * W[n*16 + k*4 + l];
    out[idx] = s;
}

__global__ void headwise_inplace_kernel(float* __restrict__ up, const float* __restrict__ W)
{
    int idx = blockIdx.x*blockDim.x + threadIdx.x;   // T*64
    if (idx >= T_TOK*64) return;
    int n = idx & 63; int t = idx >> 6;
    float* xr = up + (size_t)t*512 + n*4;
    float x0 = xr[0], x1 = xr[1], x2 = xr[2], x3 = xr[3];
    const float* w = W + n*16;
    for (int l = 0; l < 4; ++l)
        xr[l] = x0*w[l] + x1*w[4+l] + x2*w[8+l] + x3*w[12+l];
}

// ---------------- ig/fg projection ----------------
__global__ void gateproj_kernel(const float* __restrict__ q, const float* __restrict__ k,
                                const float* __restrict__ up,
                                const float* __restrict__ Wig, const float* __restrict__ big,
                                const float* __restrict__ Wfg, const float* __restrict__ bfg,
                                float* __restrict__ igt, float* __restrict__ fgt)
{
    int idx = blockIdx.x*blockDim.x + threadIdx.x;   // T*4
    if (idx >= T_TOK*NH) return;
    int hh = idx & 3; int t = idx >> 2;
    int b = t >> 8, s = t & 255;
    float si = big[hh], sf = bfg[hh];
    for (int j = 0; j < 3*INNER; ++j){
        float xv = (j < 256) ? q[(size_t)t*256 + j]
                 : (j < 512) ? k[(size_t)t*256 + j - 256]
                             : up[(size_t)t*512 + j - 512];   // v in up[:, :256]
        si += xv * Wig[j*4 + hh];
        sf += xv * Wfg[j*4 + hh];
    }
    igt[(b*4+hh)*SEQ + s] = si;
    fgt[(b*4+hh)*SEQ + s] = sf;
}

__global__ void cs_kernel(const float* __restrict__ fgt, float* __restrict__ cs)
{
    int bh = blockIdx.x*blockDim.x + threadIdx.x;    // 256
    if (bh >= BATCH*NH) return;
    float run = 0.f;
    for (int s = 0; s < SEQ; ++s){
        float f = fgt[bh*SEQ+s];
        float lf = (f > 0.f) ? -log1pf(__expf(-f)) : f - log1pf(__expf(f));
        run += lf;
        cs[bh*SEQ+s] = run;
    }
}

__global__ void maxd_kernel(const float* __restrict__ cs, const float* __restrict__ igt,
                            float* __restrict__ maxd)
{
    int idx = blockIdx.x*blockDim.x + threadIdx.x;   // 65536
    if (idx >= BATCH*NH*SEQ) return;
    int i = idx & 255; int bh = idx >> 8;
    float csi = cs[bh*SEQ+i];
    float m = -1e30f;
    for (int j = 0; j <= i; ++j) m = fmaxf(m, csi - cs[bh*SEQ+j] + igt[bh*SEQ+j]);
    maxd[idx] = m;
}

// ---------------- attention: block per (b,h), thread per row, k/v in LDS ----------
#define ACHUNK 64
__global__ void __launch_bounds__(256, 2)
attn_kernel(float* __restrict__ q, const float* __restrict__ kk,
            const float* __restrict__ up,
            const float* __restrict__ igt, const float* __restrict__ cs,
            const float* __restrict__ maxd)
{
    int bh = blockIdx.x; int b = bh >> 2, hh = bh & 3;
    int i = threadIdx.x;                             // 256 threads = rows
    __shared__ float k_sh[ACHUNK][DHM];
    __shared__ float v_sh[ACHUNK][DHM];
    __shared__ float cs_sh[SEQ], ig_sh[SEQ];
    cs_sh[i] = cs[bh*SEQ+i];
    ig_sh[i] = igt[bh*SEQ+i];
    int t_i = b*SEQ + i;
    float csi_g = cs[bh*SEQ+i];
    float m     = maxd[bh*SEQ+i];
    float* qp = q + (size_t)t_i*INNER + hh*DHM;
    float qr[DHM];
    #pragma unroll
    for (int d = 0; d < DHM; ++d) qr[d] = qp[d];
    float acc[DHM];
    #pragma unroll
    for (int d = 0; d < DHM; ++d) acc[d] = 0.f;
    float ssum = 0.f;
    for (int c0 = 0; c0 < SEQ; c0 += ACHUNK){
        __syncthreads();
        for (int idx2 = threadIdx.x; idx2 < ACHUNK*DHM; idx2 += blockDim.x){
            int j = idx2 >> 6, d = idx2 & 63;
            size_t t_j = (size_t)(b*SEQ + c0 + j);
            k_sh[j][d] = kk[t_j*INNER + hh*DHM + d];
            v_sh[j][d] = up[t_j*512  + hh*DHM + d];
        }
        __syncthreads();
        int jend = (i < c0 + ACHUNK - 1) ? i : (c0 + ACHUNK - 1);
        for (int j = c0; j <= jend; ++j){
            int jj = j - c0;
            const float4* k4 = (const float4*)k_sh[jj];
            float d0 = 0.f, d1 = 0.f, d2 = 0.f, d3 = 0.f;
            #pragma unroll
            for (int d4 = 0; d4 < 16; d4 += 4){
                float4 ka = k4[d4],   kb2 = k4[d4+1];
                float4 kc = k4[d4+2], kd  = k4[d4+3];
                d0 += qr[4*d4   ]*ka.x  + qr[4*d4+1 ]*ka.y  + qr[4*d4+2 ]*ka.z  + qr[4*d4+3 ]*ka.w;
                d1 += qr[4*d4+4 ]*kb2.x + qr[4*d4+5 ]*kb2.y + qr[4*d4+6 ]*kb2.z + qr[4*d4+7 ]*kb2.w;
                d2 += qr[4*d4+8 ]*kc.x  + qr[4*d4+9 ]*kc.y  + qr[4*d4+10]*kc.z  + qr[4*d4+11]*kc.w;
                d3 += qr[4*d4+12]*kd.x  + qr[4*d4+13]*kd.y  + qr[4*d4+14]*kd.z  + qr[4*d4+15]*kd.w;
            }
            float dot = (d0+d1) + (d2+d3);
            float arg = fminf(csi_g - cs_sh[j] + ig_sh[j] - m, 0.f);
            float cij = dot * 0.125f * __expf(arg);
            ssum += cij;
            const float4* v4 = (const float4*)v_sh[jj];
            #pragma unroll
            for (int d4 = 0; d4 < 16; ++d4){
                float4 vv = v4[d4];
                acc[4*d4]   += cij*vv.x; acc[4*d4+1] += cij*vv.y;
                acc[4*d4+2] += cij*vv.z; acc[4*d4+3] += cij*vv.w;
            }
        }
    }
    float nrm = fmaxf(fabsf(ssum), __expf(-m)) + 1e-6f;
    float rn = 1.f/nrm;
    #pragma unroll
    for (int d = 0; d < DHM; ++d) qp[d] = acc[d]*rn;
}

__global__ void mh_gate_kernel(float* __restrict__ q, const float* __restrict__ up,
                               const float* __restrict__ xc,
                               const float* __restrict__ gnw, const float* __restrict__ skip)
{
    int idx = blockIdx.x*blockDim.x + threadIdx.x;   // T*4
    if (idx >= T_TOK*NH) return;
    int hh = idx & 3; int t = idx >> 2;
    float* qp = q + (size_t)t*256 + hh*DHM;
    float s = 0.f;
    for (int d = 0; d < DHM; ++d) s += qp[d];
    float mu = s * (1.f/64.f);
    float v = 0.f;
    for (int d = 0; d < DHM; ++d){ float dv = qp[d]-mu; v += dv*dv; }
    float r = rsqrtf(v * (1.f/64.f) + 1e-6f);
    for (int d = 0; d < DHM; ++d){
        int c = hh*DHM + d;
        float hn = (qp[d]-mu)*r*gnw[c];
        float z  = up[(size_t)t*512 + 256 + c];
        qp[d] = (hn + skip[c]*xc[(size_t)t*256 + c]) * (z*sigf(z));
    }
}

// ---------------- sLSTM gate pre-activations, scan-friendly layout ----------------
__global__ void slstm_gates_kernel(const float* __restrict__ xc, const float* __restrict__ xl,
                                   const float* __restrict__ Wg, const float* __restrict__ bg,
                                   float* __restrict__ gates)
{
    int idx = blockIdx.x*blockDim.x + threadIdx.x;   // T*512, g fastest
    if (idx >= T_TOK*512) return;
    int g = idx & 3; int rest = idx >> 2;
    int l = rest & 31; rest >>= 5;
    int n = rest & 3;  int t = rest >> 2;
    int b = t >> 8, s = t & 255;
    const float* in = (g < 2) ? xc : xl;
    const float* xr = in + (size_t)t*128 + n*32;
    const float* w  = Wg + (g*4+n)*1024 + l;
    float s0 = 0.f, s1 = 0.f, s2 = 0.f, s3 = 0.f;
    #pragma unroll
    for (int k = 0; k < 32; k += 4){
        s0 = fmaf(xr[k  ], w[(k  )*32], s0);
        s1 = fmaf(xr[k+1], w[(k+1)*32], s1);
        s2 = fmaf(xr[k+2], w[(k+2)*32], s2);
        s3 = fmaf(xr[k+3], w[(k+3)*32], s3);
    }
    gates[(size_t)((b*4+n)*SEQ + s)*128 + l*4 + g] =
        bg[g*128 + n*32 + l] + (s0+s1) + (s2+s3);
}

// ---------------- sLSTM recurrence: block per (b,n), float4 gates + prefetch -------
__global__ void slstm_scan_kernel(const float* __restrict__ gates, const float* __restrict__ Rw,
                                  float* __restrict__ ys)
{
    int bn = blockIdx.x;                 // b*4 + n
    int b = bn >> 2, n = bn & 3;
    int l = threadIdx.x;                 // 32
    __shared__ float R_sh[4][32][32];    // [g][k][l]
    __shared__ float h_sh[32];
    for (int i2 = l; i2 < 4096; i2 += 32){
        int g = i2 >> 10, k = (i2 >> 5) & 31, ll = i2 & 31;
        R_sh[g][k][ll] = Rw[(g*4+n)*1024 + k*32 + ll];
    }
    h_sh[l] = 0.f;
    float c = 0.f, nst = 0.f, m = 0.f;
    __syncthreads();
    const float* gbase = gates + (size_t)bn*SEQ*128;
    float4 gcur = ((const float4*)gbase)[l];         // s = 0
    for (int s = 0; s < SEQ; ++s){
        float4 gnext;
        if (s+1 < SEQ) gnext = ((const float4*)(gbase + (size_t)(s+1)*128))[l];
        else           gnext = make_float4(0.f,0.f,0.f,0.f);
        float r0=0.f, r1=0.f, r2=0.f, r3=0.f;
        #pragma unroll 8
        for (int k = 0; k < 32; ++k){
            float hv = h_sh[k];
            r0 += hv * R_sh[0][k][l];
            r1 += hv * R_sh[1][k][l];
            r2 += hv * R_sh[2][k][l];
            r3 += hv * R_sh[3][k][l];
        }
        float ir  = gcur.x + r0;
        float fr  = gcur.y + r1;
        float zr  = gcur.z + r2;
        float orr = gcur.w + r3;
        float mnew = fmaxf(fr + m, ir);
        float iv = __expf(ir - mnew);
        float fv = __expf(fr + m - mnew);
        float zt = tanhf(zr);
        float ov = sigf(orr);
        c   = fv*c + iv*zt;
        nst = fv*nst + iv;
        float hst = ov * c / (nst + 1e-8f);
        m = mnew;
        __syncthreads();
        h_sh[l] = hst;
        ys[(size_t)(b*SEQ + s)*128 + n*32 + l] = hst;
        gcur = gnext;
        __syncthreads();
    }
}

__global__ void mh_add_kernel(const float* __restrict__ ys, const float* __restrict__ gnw,
                              float* __restrict__ h)
{
    int idx = blockIdx.x*blockDim.x + threadIdx.x;   // T*4
    if (idx >= T_TOK*SNH) return;
    int n = idx & 3; int t = idx >> 2;
    const float* yr = ys + (size_t)t*128 + n*32;
    float s = 0.f;
    for (int l = 0; l < 32; ++l) s += yr[l];
    float mu = s * (1.f/32.f);
    float v = 0.f;
    for (int l = 0; l < 32; ++l){ float dv = yr[l]-mu; v += dv*dv; }
    float r = rsqrtf(v * (1.f/32.f) + 1e-6f);
    for (int l = 0; l < 32; ++l)
        h[(size_t)t*128 + n*32 + l] += (yr[l]-mu)*r*gnw[n*32+l];
}

__global__ void geluv_kernel(const float* __restrict__ up, float* __restrict__ out)
{
    int idx = blockIdx.x*blockDim.x + threadIdx.x;   // T*192
    if (idx >= T_TOK*FF) return;
    int j = idx % FF; int t = idx / FF;
    float g  = up[(size_t)t*384 + j];
    float vv = up[(size_t)t*384 + FF + j];
    float gel = 0.5f*g*(1.f + tanhf(0.7978845608028654f*(g + 0.044715f*g*g*g)));
    out[idx] = gel*vv;
}

// ---------------- final projection: fp32 output ----------------
__global__ void out_kernel(const float* __restrict__ ln, const float* __restrict__ W,
                           const float* __restrict__ bias, float* __restrict__ out)
{
    int idx = threadIdx.x;                           // 192 threads, 1 block
    if (idx >= BATCH*3) return;
    int b = idx / 3, e = idx % 3;
    float s = bias[e];
    const float* xr = ln + ((size_t)(b*SEQ + SEQ-1))*128;
    for (int d = 0; d < 128; ++d) s += xr[d]*W[d*3+e];
    out[idx] = s;
}

#define LCHK do { \
    if (hipGetLastError() != hipSuccess){ \
        sentinel_kernel<<<1, 192, 0, stream>>>((float*)d_out, 3000.0f + 32.0f*(float)launch_idx); \
        return; } \
    ++launch_idx; } while(0)

extern "C" void kernel_launch(void* const* d_in, const int* in_sizes, int n_in,
                              void* d_out, int out_size, void* d_ws, size_t ws_size,
                              hipStream_t stream)
{
    (void)out_size;
    static const int expected_sizes[30] = {
        49152, 384, 128, 512, 262144, 4096, 1024, 4096, 4096, 4096,
        12288, 16, 12288, 16, 1024, 1024, 131072, 256, 1024, 256,
        32768, 1024, 32768, 256, 256, 98304, 49152, 128, 384, 3
    };
    if (n_in != 30){ sentinel_kernel<<<1,192,0,stream>>>((float*)d_out, 5000.0f); return; }
    for (int i = 0; i < 30; ++i)
        if (in_sizes[i] != expected_sizes[i]){
            sentinel_kernel<<<1,192,0,stream>>>((float*)d_out, 2000.0f + 32.0f*i); return; }
    if (ws_size < (size_t)96*1024*1024){
        sentinel_kernel<<<1,192,0,stream>>>((float*)d_out, 1000.0f + (float)(ws_size >> 20)); return; }

    const float* x        = (const float*)d_in[0];
    const float* W_emb    = (const float*)d_in[1];
    const float* b_emb    = (const float*)d_in[2];
    const float* m_ln_w   = (const float*)d_in[3];
    const float* m_Wup    = (const float*)d_in[4];
    const float* m_conv_w = (const float*)d_in[5];
    const float* m_conv_b = (const float*)d_in[6];
    const float* m_Wq     = (const float*)d_in[7];
    const float* m_Wk     = (const float*)d_in[8];
    const float* m_Wv     = (const float*)d_in[9];
    const float* m_Wig    = (const float*)d_in[10];
    const float* m_big    = (const float*)d_in[11];
    const float* m_Wfg    = (const float*)d_in[12];
    const float* m_bfg    = (const float*)d_in[13];
    const float* m_gn_w   = (const float*)d_in[14];
    const float* m_skip   = (const float*)d_in[15];
    const float* m_Wdown  = (const float*)d_in[16];
    const float* s_ln_w   = (const float*)d_in[17];
    const float* s_conv_w = (const float*)d_in[18];
    const float* s_conv_b = (const float*)d_in[19];
    const float* s_Wg     = (const float*)d_in[20];
    const float* s_bg     = (const float*)d_in[21];
    const float* s_R      = (const float*)d_in[22];
    const float* s_gn_w   = (const float*)d_in[23];
    const float* s_ln2_w  = (const float*)d_in[24];
    const float* s_Wff_up = (const float*)d_in[25];
    const float* s_Wff_dn = (const float*)d_in[26];
    const float* post_ln  = (const float*)d_in[27];
    const float* W_out    = (const float*)d_in[28];
    const float* b_out    = (const float*)d_in[29];

    float* ws  = (float*)d_ws;
    float* h   = ws;                         // T*128
    float* ln  = h   + (size_t)T_TOK*128;    // T*128; igt/fgt/cs/maxd alias (ln dead then)
    float* up  = ln  + (size_t)T_TOK*128;    // T*512
    float* xc  = up  + (size_t)T_TOK*512;    // T*256
    float* qb  = xc  + (size_t)T_TOK*256;    // T*256
    float* kb  = qb  + (size_t)T_TOK*256;    // T*256 (k; sLSTM ys)
    float* igt  = ln;
    float* fgt  = ln + 65536;
    float* csb  = ln + 2*65536;
    float* maxd = ln + 3*65536;

    int launch_idx = 0;
    (void)hipGetLastError();

    embed_kernel<<<(T_TOK*128)/256, 256, 0, stream>>>(x, W_emb, b_emb, h); LCHK;

    const char* bt = "msmsmm";
    int mi = 0, si = 0;
    for (int blk = 0; blk < 6; ++blk){
        if (bt[blk] == 'm'){
            ln_kernel<<<T_TOK, 64, 0, stream>>>(h, m_ln_w + mi*128, ln); LCHK;
            gemm_tiled_kernel<<<(T_TOK/TM)*(512/TN), 256, 0, stream>>>(ln, m_Wup + (size_t)mi*65536, up, T_TOK, 512, 128, 0); LCHK;
            conv_silu_kernel<<<(T_TOK*256)/256, 256, 0, stream>>>(up, 512, m_conv_w + mi*1024, m_conv_b + mi*256, xc, 256); LCHK;
            headwise_kernel<<<(T_TOK*256)/256, 256, 0, stream>>>(xc, 256, m_Wq + mi*1024, qb); LCHK;
            headwise_kernel<<<(T_TOK*256)/256, 256, 0, stream>>>(xc, 256, m_Wk + mi*1024, kb); LCHK;
            headwise_inplace_kernel<<<(T_TOK*64)/256, 256, 0, stream>>>(up, m_Wv + mi*1024); LCHK;
            gateproj_kernel<<<(T_TOK*4)/256, 256, 0, stream>>>(qb, kb, up, m_Wig + mi*3072, m_big + mi*4,
                                                               m_Wfg + mi*3072, m_bfg + mi*4, igt, fgt); LCHK;
            cs_kernel<<<4, 64, 0, stream>>>(fgt, csb); LCHK;
            maxd_kernel<<<256, 256, 0, stream>>>(csb, igt, maxd); LCHK;
            attn_kernel<<<256, 256, 0, stream>>>(qb, kb, up, igt, csb, maxd); LCHK;
            mh_gate_kernel<<<(T_TOK*4)/256, 256, 0, stream>>>(qb, up, xc, m_gn_w + mi*256, m_skip + mi*256); LCHK;
            gemm_tiled_kernel<<<(T_TOK/TM)*(128/TN), 256, 0, stream>>>(qb, m_Wdown + (size_t)mi*32768, h, T_TOK, 128, 256, 1); LCHK;
            ++mi;
        } else {
            ln_kernel<<<T_TOK, 64, 0, stream>>>(h, s_ln_w + si*128, ln); LCHK;
            conv_silu_kernel<<<(T_TOK*128)/256, 256, 0, stream>>>(ln, 128, s_conv_w + si*512, s_conv_b + si*128, xc, 128); LCHK;
            slstm_gates_kernel<<<(T_TOK*512)/256, 256, 0, stream>>>(xc, ln, s_Wg + si*16384, s_bg + si*512, up); LCHK;
            slstm_scan_kernel<<<BATCH*4, 32, 0, stream>>>(up, s_R + si*16384, kb); LCHK;
            mh_add_kernel<<<(T_TOK*4)/256, 256, 0, stream>>>(kb, s_gn_w + si*128, h); LCHK;
            ln_kernel<<<T_TOK, 64, 0, stream>>>(h, s_ln2_w + si*128, ln); LCHK;
            gemm_tiled_kernel<<<(T_TOK/TM)*(384/TN), 256, 0, stream>>>(ln, s_Wff_up + (size_t)si*49152, up, T_TOK, 384, 128, 0); LCHK;
            geluv_kernel<<<(T_TOK*192)/256, 256, 0, stream>>>(up, qb); LCHK;
            gemm_tiled_kernel<<<(T_TOK/TM)*(128/TN), 256, 0, stream>>>(qb, s_Wff_dn + (size_t)si*24576, h, T_TOK, 128, 192, 1); LCHK;
            ++si;
        }
    }

    ln_kernel<<<T_TOK, 64, 0, stream>>>(h, post_ln, ln); LCHK;
    out_kernel<<<1, 192, 0, stream>>>(ln, W_out, b_out, (float*)d_out); LCHK;
}